// Round 7
// baseline (347.056 us; speedup 1.0000x reference)
//
#include <hip/hip_runtime.h>

// VQ quantizer, fp32: z [131072,64], e [2048,64].
// d_out (flat f32): z_q [131072*64] | indices [131072] (floats) | loss [1].
//
// 2-split bf16 MFMA scan (hh, hl, lh products), argmax of s = dot - esq/2.
// 32 rows/wave, 1024 blocks (16 waves/CU) — small register footprint so the
// compiler keeps A-fragments + top-2 state resident (round-6's 84-VGPR alloc
// rematerialized the A-frag builds: VALU-busy 77us vs 25us static count).
// Top-2 gap < EPS_S flags rows into a global list; exact f64 re-solve
// (LDS-staged z row, 8 independent f64 chains, coalesced eT). T=0 =>
// z_out = z_q = e[best].

#define N_ROWS 131072
#define ZD 64
#define KCODES 2048
#define EPS_S 2e-3f          // s-scale gap; split error worst-case ~6e-4
#define FLAG_CAP 32768

using bf16x8  = __attribute__((ext_vector_type(8))) short;
using floatx4 = __attribute__((ext_vector_type(4))) float;

__device__ inline float bf2f(unsigned short u) {
    union { unsigned int i; float f; } c; c.i = ((unsigned int)u) << 16; return c.f;
}
__device__ inline unsigned short f2bf(float x) {
    union { float f; unsigned int i; } c; c.f = x;
    unsigned int b = c.i + 0x7FFFu + ((c.i >> 16) & 1u);
    return (unsigned short)(b >> 16);
}

// ws byte layout:
//       0: loss f32 | 4: flag count u32
//    4096: esn f32[2048]   (= -esq/2, summed in f64)
//   16384: esq64 f64[2048]
//   32768: ehi u16[2048*64] | 294912: elo u16[2048*64]
//  557056: eT f32[64*2048]
// 1081344: flags u32[32768]   (ends 1212416)

__global__ void prep_kernel(const float* __restrict__ e, float* __restrict__ ws) {
    int c = blockIdx.x * 256 + threadIdx.x;       // 8 blocks -> 2048 codes
    if (c == 0) { ws[0] = 0.0f; ((unsigned int*)ws)[1] = 0u; }
    float* esn = ws + 1024;
    double* esq64 = (double*)((char*)ws + 16384);
    unsigned short* ehi = (unsigned short*)((char*)ws + 32768);
    unsigned short* elo = (unsigned short*)((char*)ws + 294912);
    float* eT = (float*)((char*)ws + 557056);
    const float* p = e + (size_t)c * ZD;
    double s = 0.0;
    for (int k = 0; k < ZD; k++) {
        float x = p[k];
        s = fma((double)x, (double)x, s);
        unsigned short h = f2bf(x);
        ehi[c * ZD + k] = h;
        elo[c * ZD + k] = f2bf(x - bf2f(h));
        eT[k * KCODES + c] = x;                   // coalesced across threads
    }
    esq64[c] = s;
    esn[c] = (float)(-0.5 * s);
}

__global__ __launch_bounds__(256, 4) void vq_mfma(
        const float* __restrict__ z, const float* __restrict__ e,
        float* __restrict__ ws, float* __restrict__ out) {
    const float* esn = ws + 1024;
    const unsigned short* ehi = (const unsigned short*)((const char*)ws + 32768);
    const unsigned short* elo = (const unsigned short*)((const char*)ws + 294912);
    unsigned int* cntp  = (unsigned int*)ws + 1;
    unsigned int* flags = (unsigned int*)((char*)ws + 1081344);

    int lane = threadIdx.x & 63;
    int w    = threadIdx.x >> 6;
    int wid  = blockIdx.x * 4 + w;                // 0..4095
    int row0 = wid * 32;                          // 32 rows per wave
    int lrow = lane & 15;
    int lq   = lane >> 4;

    // Resident A fragments (hi+lo), A[m=lane&15][k=lq*8+j], kc = k-half
    bf16x8 Ah[2][2], Al[2][2];
#pragma unroll
    for (int rf = 0; rf < 2; rf++)
#pragma unroll
        for (int kc = 0; kc < 2; kc++) {
            const float* zp = z + (size_t)(row0 + rf * 16 + lrow) * ZD + kc * 32 + lq * 8;
            float xv[8];
            *(float4*)(void*)&xv[0] = *(const float4*)(const void*)zp;
            *(float4*)(void*)&xv[4] = *(const float4*)(const void*)(zp + 4);
            bf16x8 h, l;
#pragma unroll
            for (int j = 0; j < 8; j++) {
                unsigned short hb = f2bf(xv[j]);
                h[j] = (short)hb;
                l[j] = (short)f2bf(xv[j] - bf2f(hb));
            }
            Ah[rf][kc] = h; Al[rf][kc] = l;
        }

    // argmax state on s = dot - esq/2  (argmin d2 == argmax s)
    floatx4 mval[2], mv2[2], midx[2];
#pragma unroll
    for (int rf = 0; rf < 2; rf++)
#pragma unroll
        for (int r = 0; r < 4; r++) {
            mval[rf][r] = -3.0e38f; mv2[rf][r] = -3.0e38f; midx[rf][r] = 0.0f;
        }

    for (int ct = 0; ct < 128; ct++) {
        int nb = ct * 16;
        const unsigned short* bh = ehi + (size_t)(nb + lrow) * ZD + lq * 8;
        const unsigned short* bl = elo + (size_t)(nb + lrow) * ZD + lq * 8;
        bf16x8 h0 = *(const bf16x8*)(const void*)(bh);
        bf16x8 h1 = *(const bf16x8*)(const void*)(bh + 32);
        bf16x8 l0 = *(const bf16x8*)(const void*)(bl);
        bf16x8 l1 = *(const bf16x8*)(const void*)(bl + 32);
        float  en = esn[nb + lrow];
        float  fcol = (float)(nb + lrow);

#pragma unroll
        for (int rf = 0; rf < 2; rf++) {
            floatx4 acc = {en, en, en, en};       // start at -esq/2
            acc = __builtin_amdgcn_mfma_f32_16x16x32_bf16(Ah[rf][0], h0, acc, 0, 0, 0);
            acc = __builtin_amdgcn_mfma_f32_16x16x32_bf16(Ah[rf][1], h1, acc, 0, 0, 0);
            acc = __builtin_amdgcn_mfma_f32_16x16x32_bf16(Ah[rf][0], l0, acc, 0, 0, 0);
            acc = __builtin_amdgcn_mfma_f32_16x16x32_bf16(Ah[rf][1], l1, acc, 0, 0, 0);
            acc = __builtin_amdgcn_mfma_f32_16x16x32_bf16(Al[rf][0], h0, acc, 0, 0, 0);
            acc = __builtin_amdgcn_mfma_f32_16x16x32_bf16(Al[rf][1], h1, acc, 0, 0, 0);
#pragma unroll
            for (int r = 0; r < 4; r++) {
                float s  = acc[r];
                bool  gt = s > mval[rf][r];
                // second-best = median(s, best, second) = max(min(s,best),second)
                mv2[rf][r]  = fmaxf(fminf(s, mval[rf][r]), mv2[rf][r]);
                midx[rf][r] = gt ? fcol : midx[rf][r];
                mval[rf][r] = fmaxf(s, mval[rf][r]);
            }
        }
    }

    float lacc = 0.0f;
#pragma unroll
    for (int rf = 0; rf < 2; rf++)
#pragma unroll
        for (int r = 0; r < 4; r++) {
            float v = mval[rf][r], v2 = mv2[rf][r], fi = midx[rf][r];
            // top-2 max-merge across the 16 lanes of this row (ties: smaller col)
            for (int off = 1; off < 16; off <<= 1) {
                float ov  = __shfl_xor(v,  off, 64);
                float ofi = __shfl_xor(fi, off, 64);
                float ov2 = __shfl_xor(v2, off, 64);
                bool take = (ov > v) || ((ov == v) && (ofi < fi));
                float loser = take ? v : ov;
                v2 = fmaxf(fmaxf(v2, ov2), loser);
                v  = take ? ov  : v;
                fi = take ? ofi : fi;
            }
            int row = row0 + rf * 16 + lq * 4 + r;
            int idx = (int)fi;
            float4 ev = ((const float4*)(const void*)(e + (size_t)idx * ZD))[lrow];
            float4 zv = ((const float4*)(const void*)(z + (size_t)row * ZD))[lrow];
            ((float4*)(void*)(out + (size_t)row * ZD))[lrow] = ev;
            float dx = ev.x - zv.x, dy = ev.y - zv.y;
            float dz = ev.z - zv.z, dw = ev.w - zv.w;
            lacc = fmaf(dx, dx, lacc); lacc = fmaf(dy, dy, lacc);
            lacc = fmaf(dz, dz, lacc); lacc = fmaf(dw, dw, lacc);
            if (lrow == 0) {
                out[(size_t)N_ROWS * ZD + row] = fi;
                if (v - v2 < EPS_S) {
                    unsigned int i = atomicAdd(cntp, 1u);
                    if (i < FLAG_CAP) flags[i] = (unsigned int)row;
                }
            }
        }

    for (int off = 1; off < 64; off <<= 1) lacc += __shfl_xor(lacc, off, 64);
    __shared__ float sm[4];
    if (lane == 0) sm[w] = lacc;
    __syncthreads();
    if (threadIdx.x == 0) atomicAdd(ws, sm[0] + sm[1] + sm[2] + sm[3]);
}

__global__ __launch_bounds__(256) void vq_fixup(
        const float* __restrict__ z, const float* __restrict__ e,
        float* __restrict__ ws, float* __restrict__ out) {
    const double* esq64 = (const double*)((const char*)ws + 16384);
    const float* eT = (const float*)((const char*)ws + 557056);
    const unsigned int* flags = (const unsigned int*)((const char*)ws + 1081344);
    unsigned int cnt = ((const unsigned int*)ws)[1];
    if (cnt > FLAG_CAP) cnt = FLAG_CAP;

    __shared__ float zrow[ZD];
    __shared__ double sd[4]; __shared__ int si[4]; __shared__ int sbest;
    int t = threadIdx.x, lane = t & 63, w = t >> 6;

    for (unsigned int u = blockIdx.x; u < cnt; u += gridDim.x) {
        int row = (int)flags[u];
        __syncthreads();                          // protect zrow from prev iter
        if (t < ZD) zrow[t] = z[(size_t)row * ZD + t];
        __syncthreads();

        double dacc[8];
#pragma unroll
        for (int j = 0; j < 8; j++) dacc[j] = 0.0;
        for (int k = 0; k < ZD; k++) {
            double zk = (double)zrow[k];
            const float* ek = eT + k * KCODES + t;
#pragma unroll
            for (int j = 0; j < 8; j++)
                dacc[j] = fma(zk, (double)ek[256 * j], dacc[j]);
        }
        double dmin = 1.0e300; int imin = 0;
#pragma unroll
        for (int j = 0; j < 8; j++) {             // ascending c: first wins
            int c = t + 256 * j;
            double d = fma(-2.0, dacc[j], esq64[c]);
            if (d < dmin) { dmin = d; imin = c; }
        }
        for (int off = 1; off < 64; off <<= 1) {
            double od = __shfl_xor(dmin, off, 64);
            int    oi = __shfl_xor(imin, off, 64);
            if (od < dmin || (od == dmin && oi < imin)) { dmin = od; imin = oi; }
        }
        if (lane == 0) { sd[w] = dmin; si[w] = imin; }
        __syncthreads();
        if (t == 0) {
            double bd = sd[0]; int bi = si[0];
            for (int q = 1; q < 4; q++)
                if (sd[q] < bd || (sd[q] == bd && si[q] < bi)) { bd = sd[q]; bi = si[q]; }
            sbest = bi;
        }
        __syncthreads();
        int bi = sbest;
        if (t < 16)
            ((float4*)(void*)(out + (size_t)row * ZD))[t] =
                ((const float4*)(const void*)(e + (size_t)bi * ZD))[t];
        if (t == 0) out[(size_t)N_ROWS * ZD + row] = (float)bi;
        // loss correction from flips: < EPS * ~700 / 8.4M < 2e-7 — ignored.
    }
}

__global__ void finalize_kernel(const float* __restrict__ ws,
                                float* __restrict__ out) {
    out[(size_t)N_ROWS * ZD + N_ROWS] = ws[0] * (1.0f / 8388608.0f);
}

extern "C" void kernel_launch(void* const* d_in, const int* in_sizes, int n_in,
                              void* d_out, int out_size, void* d_ws, size_t ws_size,
                              hipStream_t stream) {
    const float* z = (const float*)d_in[0];
    const float* e = (const float*)d_in[1];
    float* out = (float*)d_out;
    float* ws  = (float*)d_ws;

    prep_kernel<<<dim3(8), dim3(256), 0, stream>>>(e, ws);
    vq_mfma<<<dim3(1024), dim3(256), 0, stream>>>(z, e, ws, out);
    vq_fixup<<<dim3(256), dim3(256), 0, stream>>>(z, e, ws, out);
    finalize_kernel<<<dim3(1), dim3(1), 0, stream>>>(ws, out);
}

// Round 8
// 227.591 us; speedup vs baseline: 1.5249x; 1.5249x over previous
//
#include <hip/hip_runtime.h>

// VQ quantizer, fp32: z [131072,64], e [2048,64].
// d_out (flat f32): z_q [131072*64] | indices [131072] (floats) | loss [1].
//
// 2-split bf16 MFMA scan (hh, hl, lh products), argmax of s = dot - esq/2,
// acc initialized to -esq/2. 64 rows/wave, 512 blocks, 1-deep B prefetch.
// A-fragments are PINNED via empty asm ("+v") after the build: rounds 5-7
// showed the allocator rematerializing the z-load + f2bf chain inside the
// 128-iter loop (VALU-busy 77-84us vs ~20us static; VGPR_Count 52-88).
// An asm def cannot be rematerialized -> fragments stay register-resident.
// Top-2 gap < EPS_S flags rows into a global list; exact f64 re-solve
// (LDS-staged z row, coalesced eT, f64 esq). T=0 => z_out = z_q = e[best].

#define N_ROWS 131072
#define ZD 64
#define KCODES 2048
#define EPS_S 2e-3f          // s-scale gap; realistic split error ~2e-5
#define FLAG_CAP 32768

using bf16x8  = __attribute__((ext_vector_type(8))) short;
using floatx4 = __attribute__((ext_vector_type(4))) float;

__device__ inline float bf2f(unsigned short u) {
    union { unsigned int i; float f; } c; c.i = ((unsigned int)u) << 16; return c.f;
}
__device__ inline unsigned short f2bf(float x) {
    union { float f; unsigned int i; } c; c.f = x;
    unsigned int b = c.i + 0x7FFFu + ((c.i >> 16) & 1u);
    return (unsigned short)(b >> 16);
}

// ws byte layout:
//       0: loss f32 | 4: flag count u32
//    4096: esn f32[2048]   (= -esq/2, summed in f64)
//   16384: esq64 f64[2048]
//   32768: ehi u16[2048*64] | 294912: elo u16[2048*64]
//  557056: eT f32[64*2048]
// 1081344: flags u32[32768]   (ends 1212416)

__global__ void prep_kernel(const float* __restrict__ e, float* __restrict__ ws) {
    int t = threadIdx.x, lane = t & 63, w = t >> 6;
    if (blockIdx.x == 0 && t == 0) { ws[0] = 0.0f; ((unsigned int*)ws)[1] = 0u; }
    int c = blockIdx.x * 4 + w;                   // 512 blocks x 4 waves = 2048
    float* esn = ws + 1024;
    double* esq64 = (double*)((char*)ws + 16384);
    unsigned short* ehi = (unsigned short*)((char*)ws + 32768);
    unsigned short* elo = (unsigned short*)((char*)ws + 294912);
    float* eT = (float*)((char*)ws + 557056);

    float x = e[(size_t)c * ZD + lane];           // lane = dim k, coalesced
    unsigned short h = f2bf(x);
    ehi[c * ZD + lane] = h;
    elo[c * ZD + lane] = f2bf(x - bf2f(h));
    eT[lane * KCODES + c] = x;
    double s = (double)x * (double)x;
    for (int off = 1; off < 64; off <<= 1) s += __shfl_xor(s, off, 64);
    if (lane == 0) { esq64[c] = s; esn[c] = (float)(-0.5 * s); }
}

__global__ __launch_bounds__(256, 2) void vq_mfma(
        const float* __restrict__ z, const float* __restrict__ e,
        float* __restrict__ ws, float* __restrict__ out) {
    const float* esn = ws + 1024;
    const unsigned short* ehi = (const unsigned short*)((const char*)ws + 32768);
    const unsigned short* elo = (const unsigned short*)((const char*)ws + 294912);
    unsigned int* cntp  = (unsigned int*)ws + 1;
    unsigned int* flags = (unsigned int*)((char*)ws + 1081344);

    int lane = threadIdx.x & 63;
    int w    = threadIdx.x >> 6;
    int wid  = blockIdx.x * 4 + w;                // 0..2047
    int row0 = wid * 64;                          // 64 rows per wave
    int lrow = lane & 15;
    int lq   = lane >> 4;

    // Resident A fragments (hi+lo), A[m=lane&15][k=lq*8+j], kc = k-half
    bf16x8 Ah[4][2], Al[4][2];
#pragma unroll
    for (int rf = 0; rf < 4; rf++)
#pragma unroll
        for (int kc = 0; kc < 2; kc++) {
            const float* zp = z + (size_t)(row0 + rf * 16 + lrow) * ZD + kc * 32 + lq * 8;
            float xv[8];
            *(float4*)(void*)&xv[0] = *(const float4*)(const void*)zp;
            *(float4*)(void*)&xv[4] = *(const float4*)(const void*)(zp + 4);
            bf16x8 h, l;
#pragma unroll
            for (int j = 0; j < 8; j++) {
                unsigned short hb = f2bf(xv[j]);
                h[j] = (short)hb;
                l[j] = (short)f2bf(xv[j] - bf2f(hb));
            }
            Ah[rf][kc] = h; Al[rf][kc] = l;
            // Pin: asm defs cannot be rematerialized -> stays in VGPRs.
            asm volatile("" : "+v"(Ah[rf][kc]), "+v"(Al[rf][kc]));
        }

    // argmax state on s = dot - esq/2  (argmin d2 == argmax s)
    floatx4 mval[4], mv2[4], midx[4];
#pragma unroll
    for (int rf = 0; rf < 4; rf++)
#pragma unroll
        for (int r = 0; r < 4; r++) {
            mval[rf][r] = -3.0e38f; mv2[rf][r] = -3.0e38f; midx[rf][r] = 0.0f;
        }

    const unsigned short* bh = ehi + lrow * ZD + lq * 8;
    const unsigned short* bl = elo + lrow * ZD + lq * 8;
    bf16x8 h0 = *(const bf16x8*)(const void*)(bh);
    bf16x8 h1 = *(const bf16x8*)(const void*)(bh + 32);
    bf16x8 l0 = *(const bf16x8*)(const void*)(bl);
    bf16x8 l1 = *(const bf16x8*)(const void*)(bl + 32);
    float  en = esn[lrow];

    for (int ct = 0; ct < 128; ct++) {
        // prefetch next column tile (wraps on last iter; harmless)
        int nn = ((ct + 1) & 127) * 16;
        int noff = nn * ZD;
        bf16x8 nh0 = *(const bf16x8*)(const void*)(bh + noff);
        bf16x8 nh1 = *(const bf16x8*)(const void*)(bh + noff + 32);
        bf16x8 nl0 = *(const bf16x8*)(const void*)(bl + noff);
        bf16x8 nl1 = *(const bf16x8*)(const void*)(bl + noff + 32);
        float  nen = esn[nn + lrow];
        asm volatile("" : "+v"(nh0), "+v"(nh1), "+v"(nl0), "+v"(nl1));

        float fcol = (float)(ct * 16 + lrow);
#pragma unroll
        for (int rf = 0; rf < 4; rf++) {
            floatx4 acc = {en, en, en, en};       // start at -esq/2
            acc = __builtin_amdgcn_mfma_f32_16x16x32_bf16(Ah[rf][0], h0, acc, 0, 0, 0);
            acc = __builtin_amdgcn_mfma_f32_16x16x32_bf16(Ah[rf][1], h1, acc, 0, 0, 0);
            acc = __builtin_amdgcn_mfma_f32_16x16x32_bf16(Ah[rf][0], l0, acc, 0, 0, 0);
            acc = __builtin_amdgcn_mfma_f32_16x16x32_bf16(Ah[rf][1], l1, acc, 0, 0, 0);
            acc = __builtin_amdgcn_mfma_f32_16x16x32_bf16(Al[rf][0], h0, acc, 0, 0, 0);
            acc = __builtin_amdgcn_mfma_f32_16x16x32_bf16(Al[rf][1], h1, acc, 0, 0, 0);
#pragma unroll
            for (int r = 0; r < 4; r++) {
                float s  = acc[r];
                bool  gt = s > mval[rf][r];
                mv2[rf][r]  = fmaxf(fminf(s, mval[rf][r]), mv2[rf][r]);
                midx[rf][r] = gt ? fcol : midx[rf][r];
                mval[rf][r] = fmaxf(s, mval[rf][r]);
            }
        }
        h0 = nh0; h1 = nh1; l0 = nl0; l1 = nl1; en = nen;
    }

    float lacc = 0.0f;
#pragma unroll
    for (int rf = 0; rf < 4; rf++)
#pragma unroll
        for (int r = 0; r < 4; r++) {
            float v = mval[rf][r], v2 = mv2[rf][r], fi = midx[rf][r];
            // top-2 max-merge across the 16 lanes of this row (ties: smaller col)
            for (int off = 1; off < 16; off <<= 1) {
                float ov  = __shfl_xor(v,  off, 64);
                float ofi = __shfl_xor(fi, off, 64);
                float ov2 = __shfl_xor(v2, off, 64);
                bool take = (ov > v) || ((ov == v) && (ofi < fi));
                float loser = take ? v : ov;
                v2 = fmaxf(fmaxf(v2, ov2), loser);
                v  = take ? ov  : v;
                fi = take ? ofi : fi;
            }
            int row = row0 + rf * 16 + lq * 4 + r;
            int idx = (int)fi;
            float4 ev = ((const float4*)(const void*)(e + (size_t)idx * ZD))[lrow];
            float4 zv = ((const float4*)(const void*)(z + (size_t)row * ZD))[lrow];
            ((float4*)(void*)(out + (size_t)row * ZD))[lrow] = ev;
            float dx = ev.x - zv.x, dy = ev.y - zv.y;
            float dz = ev.z - zv.z, dw = ev.w - zv.w;
            lacc = fmaf(dx, dx, lacc); lacc = fmaf(dy, dy, lacc);
            lacc = fmaf(dz, dz, lacc); lacc = fmaf(dw, dw, lacc);
            if (lrow == 0) {
                out[(size_t)N_ROWS * ZD + row] = fi;
                if (v - v2 < EPS_S) {
                    unsigned int i = atomicAdd(cntp, 1u);
                    if (i < FLAG_CAP) flags[i] = (unsigned int)row;
                }
            }
        }

    for (int off = 1; off < 64; off <<= 1) lacc += __shfl_xor(lacc, off, 64);
    __shared__ float sm[4];
    if (lane == 0) sm[w] = lacc;
    __syncthreads();
    if (threadIdx.x == 0) atomicAdd(ws, sm[0] + sm[1] + sm[2] + sm[3]);
}

__global__ __launch_bounds__(256) void vq_fixup(
        const float* __restrict__ z, const float* __restrict__ e,
        float* __restrict__ ws, float* __restrict__ out) {
    const double* esq64 = (const double*)((const char*)ws + 16384);
    const float* eT = (const float*)((const char*)ws + 557056);
    const unsigned int* flags = (const unsigned int*)((const char*)ws + 1081344);
    unsigned int cnt = ((const unsigned int*)ws)[1];
    if (cnt > FLAG_CAP) cnt = FLAG_CAP;

    __shared__ float zrow[ZD];
    __shared__ double sd[4]; __shared__ int si[4]; __shared__ int sbest;
    int t = threadIdx.x, lane = t & 63, w = t >> 6;

    for (unsigned int u = blockIdx.x; u < cnt; u += gridDim.x) {
        int row = (int)flags[u];
        __syncthreads();                          // protect zrow from prev iter
        if (t < ZD) zrow[t] = z[(size_t)row * ZD + t];
        __syncthreads();

        double dacc[8];
#pragma unroll
        for (int j = 0; j < 8; j++) dacc[j] = 0.0;
        for (int k = 0; k < ZD; k++) {
            double zk = (double)zrow[k];
            const float* ek = eT + k * KCODES + t;
#pragma unroll
            for (int j = 0; j < 8; j++)
                dacc[j] = fma(zk, (double)ek[256 * j], dacc[j]);
        }
        double dmin = 1.0e300; int imin = 0;
#pragma unroll
        for (int j = 0; j < 8; j++) {             // ascending c: first wins
            int c = t + 256 * j;
            double d = fma(-2.0, dacc[j], esq64[c]);
            if (d < dmin) { dmin = d; imin = c; }
        }
        for (int off = 1; off < 64; off <<= 1) {
            double od = __shfl_xor(dmin, off, 64);
            int    oi = __shfl_xor(imin, off, 64);
            if (od < dmin || (od == dmin && oi < imin)) { dmin = od; imin = oi; }
        }
        if (lane == 0) { sd[w] = dmin; si[w] = imin; }
        __syncthreads();
        if (t == 0) {
            double bd = sd[0]; int bi = si[0];
            for (int q = 1; q < 4; q++)
                if (sd[q] < bd || (sd[q] == bd && si[q] < bi)) { bd = sd[q]; bi = si[q]; }
            sbest = bi;
        }
        __syncthreads();
        int bi = sbest;
        if (t < 16)
            ((float4*)(void*)(out + (size_t)row * ZD))[t] =
                ((const float4*)(const void*)(e + (size_t)bi * ZD))[t];
        if (t == 0) out[(size_t)N_ROWS * ZD + row] = (float)bi;
        // loss correction from flips: < EPS * ~700 / 8.4M < 2e-7 — ignored.
    }
}

__global__ void finalize_kernel(const float* __restrict__ ws,
                                float* __restrict__ out) {
    out[(size_t)N_ROWS * ZD + N_ROWS] = ws[0] * (1.0f / 8388608.0f);
}

extern "C" void kernel_launch(void* const* d_in, const int* in_sizes, int n_in,
                              void* d_out, int out_size, void* d_ws, size_t ws_size,
                              hipStream_t stream) {
    const float* z = (const float*)d_in[0];
    const float* e = (const float*)d_in[1];
    float* out = (float*)d_out;
    float* ws  = (float*)d_ws;

    prep_kernel<<<dim3(512), dim3(256), 0, stream>>>(e, ws);
    vq_mfma<<<dim3(512), dim3(256), 0, stream>>>(z, e, ws, out);
    vq_fixup<<<dim3(256), dim3(256), 0, stream>>>(z, e, ws, out);
    finalize_kernel<<<dim3(1), dim3(1), 0, stream>>>(ws, out);
}